// Round 1
// baseline (73866.809 us; speedup 1.0000x reference)
//
#include <hip/hip_runtime.h>
#include <hip/hip_bf16.h>
#include <type_traits>

#define BB 64
#define TT 512
#define DD 1024
#define UU 1024

// ---------------------------------------------------------------------------
// Phase 1: xw[(t*B + b)*4 + gate][u] = sum_d x[b][t][d] * W_gate[d][u] + bias
// grid: (32768/64, 4096/64), block 256. 64x64 output tile, 4x4 per thread.
// ---------------------------------------------------------------------------
template <typename XT>
__global__ __launch_bounds__(256) void xw_gemm(
    const float* __restrict__ x,
    const float* __restrict__ w0, const float* __restrict__ w1,
    const float* __restrict__ w2, const float* __restrict__ w3,
    const float* __restrict__ b0, const float* __restrict__ b1,
    const float* __restrict__ b2, const float* __restrict__ b3,
    XT* __restrict__ xw)
{
    __shared__ float As[16][68];  // As[k][m], row stride 68 floats -> 16B-aligned rows
    __shared__ float Bs[16][64];  // Bs[k][n]

    const int m0 = blockIdx.x * 64;        // row block within 32768 (= b*T + t)
    const int n0 = blockIdx.y * 64;        // col block within 4096
    const int gate = n0 >> 10;
    const int ncol0 = n0 & 1023;

    const float* __restrict__ W    = (gate == 0) ? w0 : (gate == 1) ? w1 : (gate == 2) ? w2 : w3;
    const float* __restrict__ bias = (gate == 0) ? b0 : (gate == 1) ? b1 : (gate == 2) ? b2 : b3;

    const int tid = threadIdx.x;
    const int tx = tid & 15;   // n dir (4 cols each)
    const int ty = tid >> 4;   // m dir (4 rows each)

    // x-tile load mapping: 64 rows x 16 k, float4 per thread
    const int lrow = tid >> 2;          // 0..63
    const int lk   = (tid & 3) << 2;    // 0,4,8,12
    // W-tile load mapping: 16 k x 64 n, float4 per thread
    const int wk = tid >> 4;            // 0..15
    const int wc = (tid & 15) << 2;     // 0..60

    float acc[4][4] = {};

    for (int k0 = 0; k0 < DD; k0 += 16) {
        float4 xa = *reinterpret_cast<const float4*>(&x[(size_t)(m0 + lrow) * DD + k0 + lk]);
        As[lk + 0][lrow] = xa.x;
        As[lk + 1][lrow] = xa.y;
        As[lk + 2][lrow] = xa.z;
        As[lk + 3][lrow] = xa.w;
        float4 wa = *reinterpret_cast<const float4*>(&W[(size_t)(k0 + wk) * UU + ncol0 + wc]);
        *reinterpret_cast<float4*>(&Bs[wk][wc]) = wa;
        __syncthreads();
#pragma unroll
        for (int kk = 0; kk < 16; ++kk) {
            float4 a4 = *reinterpret_cast<const float4*>(&As[kk][ty << 2]);
            float4 b4 = *reinterpret_cast<const float4*>(&Bs[kk][tx << 2]);
            float a[4] = {a4.x, a4.y, a4.z, a4.w};
            float b[4] = {b4.x, b4.y, b4.z, b4.w};
#pragma unroll
            for (int i = 0; i < 4; ++i)
#pragma unroll
                for (int j = 0; j < 4; ++j) acc[i][j] += a[i] * b[j];
        }
        __syncthreads();
    }

    const int r_base = m0 + (ty << 2);
    const int u_base = ncol0 + (tx << 2);
    float bs[4];
#pragma unroll
    for (int j = 0; j < 4; ++j) bs[j] = bias[u_base + j];
#pragma unroll
    for (int i = 0; i < 4; ++i) {
        int r = r_base + i;
        int bbi = r >> 9;   // b = r / 512
        int tti = r & 511;  // t = r % 512
        size_t off = (((size_t)tti * BB + bbi) * 4 + gate) * UU + u_base;
#pragma unroll
        for (int j = 0; j < 4; ++j) {
            float v = acc[i][j] + bs[j];
            if constexpr (std::is_same<XT, float>::value)
                xw[off + j] = v;
            else
                xw[off + j] = __float2bfloat16(v);
        }
    }
}

// ---------------------------------------------------------------------------
// h0 broadcast: h[b][u] = h0[u]
// ---------------------------------------------------------------------------
__global__ __launch_bounds__(256) void bcast_h0(const float* __restrict__ h0,
                                                float* __restrict__ h)
{
    int i = blockIdx.x * 256 + threadIdx.x;  // 65536 total
    h[i] = h0[i & (UU - 1)];
}

// ---------------------------------------------------------------------------
// Phase 2, one timestep:
//   g = xw_t + h @ [fu|iu|cu|ou]; h1 = sig(f)*h + sig(i)*tanh(c);
//   y = sig(o)*tanh(h1)
// grid 256 (4 b-blocks x 64 u-blocks), block 256 (16 b x 16 u), 1 thread per
// (b,u) computing 4 gate dot products; h staged in LDS in 64-wide k tiles.
// ---------------------------------------------------------------------------
template <typename XT>
__global__ __launch_bounds__(256) void lstm_step(
    const XT* __restrict__ xw, const float* __restrict__ hprev,
    float* __restrict__ hnext,
    const float* __restrict__ fu, const float* __restrict__ iu,
    const float* __restrict__ cu, const float* __restrict__ ou,
    float* __restrict__ y, int t)
{
    __shared__ float hs[16][65];

    const int tid = threadIdx.x;
    const int tx = tid & 15;                  // u local
    const int ty = tid >> 4;                  // b local
    const int b0 = (blockIdx.x >> 6) << 4;    // 0,16,32,48
    const int u0 = (blockIdx.x & 63) << 4;    // 0..1008
    const int b = b0 + ty;
    const int u = u0 + tx;

    // xw base for this (t, b): gates at stride UU
    size_t xbase = (((size_t)t * BB + b) * 4) * UU + u;
    float gf, gi, gc, go;
    if constexpr (std::is_same<XT, float>::value) {
        gf = xw[xbase + 0 * UU];
        gi = xw[xbase + 1 * UU];
        gc = xw[xbase + 2 * UU];
        go = xw[xbase + 3 * UU];
    } else {
        gf = __bfloat162float(xw[xbase + 0 * UU]);
        gi = __bfloat162float(xw[xbase + 1 * UU]);
        gc = __bfloat162float(xw[xbase + 2 * UU]);
        go = __bfloat162float(xw[xbase + 3 * UU]);
    }

    const int lr = tid >> 6;   // 0..3
    const int lc = tid & 63;   // 0..63

    for (int k0 = 0; k0 < UU; k0 += 64) {
#pragma unroll
        for (int i = 0; i < 4; ++i)
            hs[lr * 4 + i][lc] = hprev[(size_t)(b0 + lr * 4 + i) * UU + k0 + lc];
        __syncthreads();
#pragma unroll 8
        for (int k = 0; k < 64; ++k) {
            float hv = hs[ty][k];
            int uoff = (k0 + k) * UU + u;
            gf += hv * fu[uoff];
            gi += hv * iu[uoff];
            gc += hv * cu[uoff];
            go += hv * ou[uoff];
        }
        __syncthreads();
    }

    float f = 1.0f / (1.0f + expf(-gf));
    float i_ = 1.0f / (1.0f + expf(-gi));
    float c = tanhf(gc);
    float o = 1.0f / (1.0f + expf(-go));
    float hp = hprev[(size_t)b * UU + u];
    float h1 = f * hp + i_ * c;
    float yv = o * tanhf(h1);
    hnext[(size_t)b * UU + u] = h1;
    y[((size_t)b * TT + t) * UU + u] = yv;
}

// ---------------------------------------------------------------------------
extern "C" void kernel_launch(void* const* d_in, const int* in_sizes, int n_in,
                              void* d_out, int out_size, void* d_ws, size_t ws_size,
                              hipStream_t stream)
{
    const float* x  = (const float*)d_in[0];
    const float* fw = (const float*)d_in[1];
    const float* fu = (const float*)d_in[2];
    const float* fb = (const float*)d_in[3];
    const float* iw = (const float*)d_in[4];
    const float* iu = (const float*)d_in[5];
    const float* ib = (const float*)d_in[6];
    const float* cw = (const float*)d_in[7];
    const float* cu = (const float*)d_in[8];
    const float* cb = (const float*)d_in[9];
    const float* ow = (const float*)d_in[10];
    const float* ou = (const float*)d_in[11];
    const float* ob = (const float*)d_in[12];
    const float* h0 = (const float*)d_in[13];
    float* y = (float*)d_out;

    const size_t xw_elems = (size_t)TT * BB * 4 * UU;      // 134,217,728
    const size_t h_elems  = (size_t)BB * UU;               // 65,536
    const size_t f32_need = xw_elems * 4 + 2 * h_elems * 4;

    char* wsb = (char*)d_ws;
    dim3 g1(32768 / 64, 4096 / 64);

    if (ws_size >= f32_need) {
        float* xw = (float*)wsb;
        float* hA = (float*)(wsb + xw_elems * 4);
        float* hB = hA + h_elems;

        xw_gemm<float><<<g1, 256, 0, stream>>>(x, fw, iw, cw, ow, fb, ib, cb, ob, xw);
        bcast_h0<<<256, 256, 0, stream>>>(h0, hA);
        for (int t = 0; t < TT; ++t) {
            const float* hp = (t & 1) ? hB : hA;
            float*       hn = (t & 1) ? hA : hB;
            lstm_step<float><<<256, 256, 0, stream>>>(xw, hp, hn, fu, iu, cu, ou, y, t);
        }
    } else {
        __hip_bfloat16* xw = (__hip_bfloat16*)wsb;
        float* hA = (float*)(wsb + xw_elems * 2);
        float* hB = hA + h_elems;

        xw_gemm<__hip_bfloat16><<<g1, 256, 0, stream>>>(x, fw, iw, cw, ow, fb, ib, cb, ob, xw);
        bcast_h0<<<256, 256, 0, stream>>>(h0, hA);
        for (int t = 0; t < TT; ++t) {
            const float* hp = (t & 1) ? hB : hA;
            float*       hn = (t & 1) ? hA : hB;
            lstm_step<__hip_bfloat16><<<256, 256, 0, stream>>>(xw, hp, hn, fu, iu, cu, ou, y, t);
        }
    }
}

// Round 2
// 3150.636 us; speedup vs baseline: 23.4450x; 23.4450x over previous
//
#include <hip/hip_runtime.h>
#include <hip/hip_bf16.h>
#include <type_traits>

#define BB 64
#define TT 512
#define DD 1024
#define UU 1024

typedef __attribute__((ext_vector_type(8))) short short8;
typedef __attribute__((ext_vector_type(4))) float f32x4;

static __device__ __forceinline__ unsigned short f2bf(float f) {
    unsigned int u = __float_as_uint(f);
    unsigned int r = (u + 0x7fffu + ((u >> 16) & 1u)) >> 16;   // RNE
    return (unsigned short)r;
}
static __device__ __forceinline__ float bf2f(unsigned short s) {
    return __uint_as_float(((unsigned int)s) << 16);
}

template <typename XT>
static __device__ __forceinline__ float xwld(const XT* p, size_t i) {
    if constexpr (std::is_same<XT, float>::value) return p[i];
    else return bf2f((unsigned short)p[i]);
}

// ---------------------------------------------------------------------------
// Pack a logical (1024 x 4096) weight [k][gate*1024+u] into MFMA B-fragment
// layout: out[((n16*32 + kb)*64 + lane)*8 + i] = W[kb*32 + (lane>>4)*8 + i][n16*16 + (lane&15)]
// ---------------------------------------------------------------------------
__global__ __launch_bounds__(256) void pack_w(
    const float* __restrict__ w0, const float* __restrict__ w1,
    const float* __restrict__ w2, const float* __restrict__ w3,
    short* __restrict__ out)
{
    int tid = blockIdx.x * 256 + threadIdx.x;   // 524288 threads
    int lane = tid & 63;
    int kb = (tid >> 6) & 31;
    int n16 = tid >> 11;
    int col = (n16 << 4) + (lane & 15);
    int g = col >> 10, u = col & 1023;
    const float* __restrict__ src = (g == 0) ? w0 : (g == 1) ? w1 : (g == 2) ? w2 : w3;
    int kbase = kb * 32 + ((lane >> 4) << 3);
    short8 p;
#pragma unroll
    for (int i = 0; i < 8; ++i) p[i] = (short)f2bf(src[(size_t)(kbase + i) * UU + u]);
    *reinterpret_cast<short8*>(out + (size_t)tid * 8) = p;
}

// ---------------------------------------------------------------------------
// init: h (f32 and bf16) broadcast from h0
// ---------------------------------------------------------------------------
__global__ __launch_bounds__(256) void init_h(const float* __restrict__ h0,
                                              float* __restrict__ hf,
                                              unsigned short* __restrict__ hb)
{
    int i = blockIdx.x * 256 + threadIdx.x;  // 65536
    float v = h0[i & (UU - 1)];
    hf[i] = v;
    hb[i] = f2bf(v);
}

// ---------------------------------------------------------------------------
// Phase 1: xw = x @ [fw|iw|cw|ow] + bias, MFMA bf16.
// Block 256 thr = 4 waves (2x2), block tile 128x128, wave tile 64x64.
// grid (32 nblk, 256 mblk).
// ---------------------------------------------------------------------------
template <typename XT>
__global__ __launch_bounds__(256) void gemm_xw(
    const float* __restrict__ x, const short* __restrict__ wpk,
    const float* __restrict__ fb, const float* __restrict__ ib,
    const float* __restrict__ cb, const float* __restrict__ ob,
    XT* __restrict__ xw)
{
    __shared__ short As[128 * 40];   // 128 rows x (32 + 8 pad) bf16
    __shared__ short Bs[8 * 512];    // 8 n16-tiles x 512

    const int tid = threadIdx.x;
    const int lane = tid & 63;
    const int wid = tid >> 6;
    const int wr = wid >> 1, wc = wid & 1;
    const int n0 = blockIdx.x << 7;
    const int m0 = blockIdx.y << 7;
    const int n16b = n0 >> 4;

    // A staging mapping
    const int srow = tid >> 1;
    const int kh = tid & 1;
    const float* __restrict__ xrow = x + (size_t)(m0 + srow) * DD + kh * 16;
    // B staging mapping
    const short* __restrict__ wsrc =
        wpk + ((size_t)(n16b + (tid >> 5)) * 32) * 512 + (size_t)(tid & 31) * 16;

    f32x4 acc[4][4];
#pragma unroll
    for (int i = 0; i < 4; ++i)
#pragma unroll
        for (int j = 0; j < 4; ++j) acc[i][j] = (f32x4){0.f, 0.f, 0.f, 0.f};

    const int aoff = (wr * 64 + (lane & 15)) * 40 + (lane >> 4) * 8;
    const int boff = (wc * 4) * 512 + lane * 8;

    for (int kb = 0; kb < 32; ++kb) {
        const float4* xp = reinterpret_cast<const float4*>(xrow + kb * 32);
        float4 v0 = xp[0], v1 = xp[1], v2 = xp[2], v3 = xp[3];
        short8 p0, p1;
        p0[0] = (short)f2bf(v0.x); p0[1] = (short)f2bf(v0.y);
        p0[2] = (short)f2bf(v0.z); p0[3] = (short)f2bf(v0.w);
        p0[4] = (short)f2bf(v1.x); p0[5] = (short)f2bf(v1.y);
        p0[6] = (short)f2bf(v1.z); p0[7] = (short)f2bf(v1.w);
        p1[0] = (short)f2bf(v2.x); p1[1] = (short)f2bf(v2.y);
        p1[2] = (short)f2bf(v2.z); p1[3] = (short)f2bf(v2.w);
        p1[4] = (short)f2bf(v3.x); p1[5] = (short)f2bf(v3.y);
        p1[6] = (short)f2bf(v3.z); p1[7] = (short)f2bf(v3.w);
        *reinterpret_cast<short8*>(&As[srow * 40 + kh * 16]) = p0;
        *reinterpret_cast<short8*>(&As[srow * 40 + kh * 16 + 8]) = p1;

        const short8* ws8 = reinterpret_cast<const short8*>(wsrc + (size_t)kb * 512);
        short8 b0v = ws8[0], b1v = ws8[1];
        *reinterpret_cast<short8*>(&Bs[tid * 16]) = b0v;
        *reinterpret_cast<short8*>(&Bs[tid * 16 + 8]) = b1v;
        __syncthreads();

        short8 af[4], bfr[4];
#pragma unroll
        for (int fi = 0; fi < 4; ++fi)
            af[fi] = *reinterpret_cast<const short8*>(&As[aoff + fi * 640]);
#pragma unroll
        for (int fj = 0; fj < 4; ++fj)
            bfr[fj] = *reinterpret_cast<const short8*>(&Bs[boff + fj * 512]);
#pragma unroll
        for (int fi = 0; fi < 4; ++fi)
#pragma unroll
            for (int fj = 0; fj < 4; ++fj)
                acc[fi][fj] = __builtin_amdgcn_mfma_f32_16x16x32_bf16(
                    af[fi], bfr[fj], acc[fi][fj], 0, 0, 0);
        __syncthreads();
    }

    const int g = n0 >> 10;
    const float* __restrict__ bias = (g == 0) ? fb : (g == 1) ? ib : (g == 2) ? cb : ob;
#pragma unroll
    for (int fi = 0; fi < 4; ++fi) {
#pragma unroll
        for (int fj = 0; fj < 4; ++fj) {
            int n = n0 + wc * 64 + fj * 16 + (lane & 15);
            float bv = bias[n & 1023];
#pragma unroll
            for (int r = 0; r < 4; ++r) {
                int row = m0 + wr * 64 + fi * 16 + (lane >> 4) * 4 + r;
                int b = row >> 9, t = row & 511;
                float v = acc[fi][fj][r] + bv;
                size_t off = ((size_t)t * BB + b) * 4096 + n;
                if constexpr (std::is_same<XT, float>::value) xw[off] = v;
                else xw[off] = (XT)f2bf(v);
            }
        }
    }
}

// ---------------------------------------------------------------------------
// Phase 2, one timestep, MFMA. Block 256 thr = 4 waves; wave g computes gate
// g's (16 b x 16 u) pre-activation tile. grid 256: bblk(4) x ublk(64).
// ---------------------------------------------------------------------------
template <typename XT>
__global__ __launch_bounds__(256) void lstm_step_mfma(
    const XT* __restrict__ xw,
    const float* __restrict__ hprev, const unsigned short* __restrict__ hprev_bf,
    float* __restrict__ hnext, unsigned short* __restrict__ hnext_bf,
    const short* __restrict__ upk, float* __restrict__ y, int t)
{
    __shared__ short Hs[16 * 1032];         // 16 rows x (1024 + 8 pad) bf16
    __shared__ float gbuf[4][16][17];

    const int tid = threadIdx.x;
    const int lane = tid & 63;
    const int g = tid >> 6;                 // wave index = gate
    const int bblk = blockIdx.x >> 6;
    const int ublk = blockIdx.x & 63;
    const int b0 = bblk << 4;
    const int u0 = ublk << 4;

    // stage 16 h rows (bf16) into LDS, padded rows
    const unsigned short* __restrict__ hsrc = hprev_bf + (size_t)b0 * UU;
#pragma unroll
    for (int j = 0; j < 8; ++j) {
        int gc = j * 256 + tid;             // 16B chunk id, 0..2047
        int r = gc >> 7, c = gc & 127;
        *reinterpret_cast<short8*>(&Hs[r * 1032 + c * 8]) =
            *reinterpret_cast<const short8*>(&hsrc[(size_t)gc * 8]);
    }
    __syncthreads();

    const int n16 = (g << 6) + ublk;
    const short* __restrict__ bptr = upk + (size_t)n16 * 32 * 512 + lane * 8;
    const int aoff = (lane & 15) * 1032 + (lane >> 4) * 8;

    f32x4 acc0 = (f32x4){0.f, 0.f, 0.f, 0.f};
    f32x4 acc1 = (f32x4){0.f, 0.f, 0.f, 0.f};
#pragma unroll 4
    for (int kb = 0; kb < 32; kb += 2) {
        short8 a0 = *reinterpret_cast<const short8*>(&Hs[aoff + kb * 32]);
        short8 b0v = *reinterpret_cast<const short8*>(bptr + (size_t)kb * 512);
        short8 a1 = *reinterpret_cast<const short8*>(&Hs[aoff + kb * 32 + 32]);
        short8 b1v = *reinterpret_cast<const short8*>(bptr + (size_t)kb * 512 + 512);
        acc0 = __builtin_amdgcn_mfma_f32_16x16x32_bf16(a0, b0v, acc0, 0, 0, 0);
        acc1 = __builtin_amdgcn_mfma_f32_16x16x32_bf16(a1, b1v, acc1, 0, 0, 0);
    }
    acc0[0] += acc1[0]; acc0[1] += acc1[1]; acc0[2] += acc1[2]; acc0[3] += acc1[3];

#pragma unroll
    for (int r = 0; r < 4; ++r)
        gbuf[g][(lane >> 4) * 4 + r][lane & 15] = acc0[r];
    __syncthreads();

    // elementwise tail: one thread per (b,u)
    const int bl = tid >> 4, ul = tid & 15;
    const int b = b0 + bl, u = u0 + ul;
    size_t xbase = ((size_t)t * BB + b) * 4096 + u0 + ul;
    float gf = gbuf[0][bl][ul] + xwld(xw, xbase);
    float gi = gbuf[1][bl][ul] + xwld(xw, xbase + 1024);
    float gc = gbuf[2][bl][ul] + xwld(xw, xbase + 2048);
    float go = gbuf[3][bl][ul] + xwld(xw, xbase + 3072);

    float f  = 1.0f / (1.0f + __expf(-gf));
    float i_ = 1.0f / (1.0f + __expf(-gi));
    float c  = tanhf(gc);
    float o  = 1.0f / (1.0f + __expf(-go));
    float hp = hprev[(size_t)b * UU + u];
    float h1 = f * hp + i_ * c;
    float yv = o * tanhf(h1);
    hnext[(size_t)b * UU + u] = h1;
    hnext_bf[(size_t)b * UU + u] = f2bf(h1);
    y[((size_t)b * TT + t) * UU + u] = yv;
}

// ---------------------------------------------------------------------------
extern "C" void kernel_launch(void* const* d_in, const int* in_sizes, int n_in,
                              void* d_out, int out_size, void* d_ws, size_t ws_size,
                              hipStream_t stream)
{
    const float* x  = (const float*)d_in[0];
    const float* fw = (const float*)d_in[1];
    const float* fu = (const float*)d_in[2];
    const float* fb = (const float*)d_in[3];
    const float* iw = (const float*)d_in[4];
    const float* iu = (const float*)d_in[5];
    const float* ib = (const float*)d_in[6];
    const float* cw = (const float*)d_in[7];
    const float* cu = (const float*)d_in[8];
    const float* cb = (const float*)d_in[9];
    const float* ow = (const float*)d_in[10];
    const float* ou = (const float*)d_in[11];
    const float* ob = (const float*)d_in[12];
    const float* h0 = (const float*)d_in[13];
    float* y = (float*)d_out;

    const size_t xw_elems  = (size_t)TT * BB * 4 * UU;       // 134,217,728
    const size_t pk_elems  = (size_t)4 * 1024 * 1024;        // 4,194,304 per packed weight
    const size_t h_elems   = (size_t)BB * UU;                // 65,536
    const size_t tail      = 2 * pk_elems * 2 + 2 * h_elems * 4 + 2 * h_elems * 2;
    const bool usef32 = ws_size >= xw_elems * 4 + tail;

    char* p = (char*)d_ws;
    size_t xwb = usef32 ? xw_elems * 4 : xw_elems * 2;
    short* upk = (short*)(p + xwb);
    short* wpk = upk + pk_elems;
    float* hA  = (float*)(wpk + pk_elems);
    float* hB  = hA + h_elems;
    unsigned short* hbA = (unsigned short*)(hB + h_elems);
    unsigned short* hbB = hbA + h_elems;

    pack_w<<<2048, 256, 0, stream>>>(fu, iu, cu, ou, upk);
    pack_w<<<2048, 256, 0, stream>>>(fw, iw, cw, ow, wpk);
    init_h<<<256, 256, 0, stream>>>(h0, hA, hbA);

    if (usef32) {
        float* xw = (float*)p;
        gemm_xw<float><<<dim3(32, 256), 256, 0, stream>>>(x, wpk, fb, ib, cb, ob, xw);
        for (int t = 0; t < TT; ++t) {
            const float* hp = (t & 1) ? hB : hA;
            float*       hn = (t & 1) ? hA : hB;
            const unsigned short* hbp = (t & 1) ? hbB : hbA;
            unsigned short*       hbn = (t & 1) ? hbA : hbB;
            lstm_step_mfma<float><<<256, 256, 0, stream>>>(xw, hp, hbp, hn, hbn, upk, y, t);
        }
    } else {
        unsigned short* xw = (unsigned short*)p;
        gemm_xw<unsigned short><<<dim3(32, 256), 256, 0, stream>>>(x, wpk, fb, ib, cb, ob, xw);
        for (int t = 0; t < TT; ++t) {
            const float* hp = (t & 1) ? hB : hA;
            float*       hn = (t & 1) ? hA : hB;
            const unsigned short* hbp = (t & 1) ? hbB : hbA;
            unsigned short*       hbn = (t & 1) ? hbA : hbB;
            lstm_step_mfma<unsigned short><<<256, 256, 0, stream>>>(xw, hp, hbp, hn, hbn, upk, y, t);
        }
    }
}